// Round 6
// baseline (75.663 us; speedup 1.0000x reference)
//
#include <hip/hip_runtime.h>

#define PAD 4

// out[n,c,i,j] = x[n,c, clamp(i+hs[n]-PAD,0,H-1), clamp(j+ws[n]-PAD,0,W-1)]
// N=256, C=12, H=128, W=128, fp32.
//
// Round 6: maximize memory-level parallelism. Round 5's VGPR_Count=24 showed
// the compiler serialized the k-loop (1 load chain in flight). Here all 4-8
// row loads are issued into named registers BEFORE any select/store, and
// __launch_bounds__(256,4) lifts the VGPR cap so they stay in flight.
//  - blockIdx.y = n -> hs/ws wave-uniform, no int div.
//  - Block = 32 rows of one plane; thread owns col quad j0 in rows i0+{0,8,16,24}.
//  - Interior: aligned quad loads + in-register realign (s wave-uniform).
//  - Stores: __builtin_nontemporal_store (nt only — coherent; sc0/sc1 bypass
//    broke readback in round 4).

using vf4 = __attribute__((ext_vector_type(4))) float;

__device__ __forceinline__ int clampi(int v, int lo, int hi) {
    return v < lo ? lo : (v > hi ? hi : v);
}

__global__ __launch_bounds__(256, 4) void random_shift_kernel(
    const float* __restrict__ x,
    const int*   __restrict__ h_starts,
    const int*   __restrict__ w_starts,
    float*       __restrict__ out)
{
    constexpr int W = 128, H = 128;
    constexpr int PLANE  = H * W;        // 16384 floats
    constexpr int SAMPLE = 12 * PLANE;   // 196608 floats

    const int n  = blockIdx.y;
    const int ws = w_starts[n] - PAD;    // [-4, 4], wave-uniform
    const int hs = h_starts[n] - PAD;

    const int bx      = blockIdx.x;
    const int c       = bx >> 2;         // plane (4 blocks per plane)
    const int rowbase = (bx & 3) << 5;   // 32-row chunk

    const int t  = threadIdx.x;
    const int r  = t >> 5;               // [0, 8)
    const int j0 = (t & 31) << 2;        // column quad start

    const float* __restrict__ xp = x   + (size_t)n * SAMPLE + (size_t)c * PLANE;
    float*       __restrict__ op = out + (size_t)n * SAMPLE + (size_t)c * PLANE;

    const int i0 = rowbase + r;          // rows i0 + 8k, k = 0..3
    const int sj = j0 + ws;

    // Clamped source rows for all 4 outputs, computed up front.
    const int si0 = clampi(i0      + hs, 0, H - 1);
    const int si1 = clampi(i0 + 8  + hs, 0, H - 1);
    const int si2 = clampi(i0 + 16 + hs, 0, H - 1);
    const int si3 = clampi(i0 + 24 + hs, 0, H - 1);

    float* o0 = op + (i0     ) * W + j0;
    float* o1 = op + (i0 +  8) * W + j0;
    float* o2 = op + (i0 + 16) * W + j0;
    float* o3 = op + (i0 + 24) * W + j0;

    if (sj >= 0 && sj <= W - 4) {
        const int q = sj >> 2;           // [0, 31]
        const int s = sj & 3;            // wave-uniform
        const vf4* r0 = reinterpret_cast<const vf4*>(xp + si0 * W);
        const vf4* r1 = reinterpret_cast<const vf4*>(xp + si1 * W);
        const vf4* r2 = reinterpret_cast<const vf4*>(xp + si2 * W);
        const vf4* r3 = reinterpret_cast<const vf4*>(xp + si3 * W);

        vf4 v0, v1, v2, v3;
        if (s == 0) {
            // 4 independent loads in flight.
            v0 = r0[q]; v1 = r1[q]; v2 = r2[q]; v3 = r3[q];
        } else {
            // 8 independent loads issued before any select.
            vf4 A0 = r0[q], A1 = r1[q], A2 = r2[q], A3 = r3[q];
            vf4 B0 = r0[q+1], B1 = r1[q+1], B2 = r2[q+1], B3 = r3[q+1];
            if (s == 1) {
                v0 = (vf4){A0.y, A0.z, A0.w, B0.x};
                v1 = (vf4){A1.y, A1.z, A1.w, B1.x};
                v2 = (vf4){A2.y, A2.z, A2.w, B2.x};
                v3 = (vf4){A3.y, A3.z, A3.w, B3.x};
            } else if (s == 2) {
                v0 = (vf4){A0.z, A0.w, B0.x, B0.y};
                v1 = (vf4){A1.z, A1.w, B1.x, B1.y};
                v2 = (vf4){A2.z, A2.w, B2.x, B2.y};
                v3 = (vf4){A3.z, A3.w, B3.x, B3.y};
            } else {
                v0 = (vf4){A0.w, B0.x, B0.y, B0.z};
                v1 = (vf4){A1.w, B1.x, B1.y, B1.z};
                v2 = (vf4){A2.w, B2.x, B2.y, B2.z};
                v3 = (vf4){A3.w, B3.x, B3.y, B3.z};
            }
        }
        __builtin_nontemporal_store(v0, reinterpret_cast<vf4*>(o0));
        __builtin_nontemporal_store(v1, reinterpret_cast<vf4*>(o1));
        __builtin_nontemporal_store(v2, reinterpret_cast<vf4*>(o2));
        __builtin_nontemporal_store(v3, reinterpret_cast<vf4*>(o3));
    } else {
        // Edge path: per-element column clamp, loads hoisted ahead of stores.
        const int j0c = clampi(sj + 0, 0, W - 1);
        const int j1c = clampi(sj + 1, 0, W - 1);
        const int j2c = clampi(sj + 2, 0, W - 1);
        const int j3c = clampi(sj + 3, 0, W - 1);
        const float* p0 = xp + si0 * W;
        const float* p1 = xp + si1 * W;
        const float* p2 = xp + si2 * W;
        const float* p3 = xp + si3 * W;
        vf4 v0 = (vf4){p0[j0c], p0[j1c], p0[j2c], p0[j3c]};
        vf4 v1 = (vf4){p1[j0c], p1[j1c], p1[j2c], p1[j3c]};
        vf4 v2 = (vf4){p2[j0c], p2[j1c], p2[j2c], p2[j3c]};
        vf4 v3 = (vf4){p3[j0c], p3[j1c], p3[j2c], p3[j3c]};
        __builtin_nontemporal_store(v0, reinterpret_cast<vf4*>(o0));
        __builtin_nontemporal_store(v1, reinterpret_cast<vf4*>(o1));
        __builtin_nontemporal_store(v2, reinterpret_cast<vf4*>(o2));
        __builtin_nontemporal_store(v3, reinterpret_cast<vf4*>(o3));
    }
}

extern "C" void kernel_launch(void* const* d_in, const int* in_sizes, int n_in,
                              void* d_out, int out_size, void* d_ws, size_t ws_size,
                              hipStream_t stream) {
    const float* x        = (const float*)d_in[0];
    const int*   h_starts = (const int*)d_in[1];
    const int*   w_starts = (const int*)d_in[2];
    float*       out      = (float*)d_out;

    // 12 planes x 4 row-chunks = 48 blocks in x; 256 samples in y.
    dim3 grid(48, 256);
    dim3 block(256);

    random_shift_kernel<<<grid, block, 0, stream>>>(x, h_starts, w_starts, out);
}

// Round 7
// 63.059 us; speedup vs baseline: 1.1999x; 1.1999x over previous
//
#include <hip/hip_runtime.h>

#define PAD 4

// out[n,c,i,j] = x[n,c, clamp(i+hs[n]-PAD,0,H-1), clamp(j+ws[n]-PAD,0,W-1)]
// N=256, C=12, H=128, W=128, fp32.
//
// Round 7 = exact revert to the round-3 kernel (best measured: 63.2 us,
// 6.38 TB/s logical — above the 6.29 TB/s D2D copy ceiling, courtesy of
// partial L3 read residency). Rounds 5/6 showed that hoisting / explicit
// MLP only raise VGPRs and regress: this op wants maximum TLP and a
// minimal 12-VGPR body.
//  - 2D grid: blockIdx.y = n -> hs/ws are wave-uniform scalar loads, no
//    integer division anywhere.
//  - 4 float4 per thread, block-strided (stride 256 f4) -> coalesced, 4
//    independent load->store chains, setup amortized.
//  - Read realign: interior threads load 1-2 ALIGNED float4 and realign in
//    registers (s = sj&3 is wave-uniform); edge threads (<=1 per 32-quad row)
//    take the 4-scalar-clamped-load path under exec mask.
//  - Nontemporal stores (nt only — coherent; sc0/sc1 bypass broke readback).

using vf4 = __attribute__((ext_vector_type(4))) float;

__global__ __launch_bounds__(256) void random_shift_kernel(
    const float* __restrict__ x,
    const int*   __restrict__ h_starts,
    const int*   __restrict__ w_starts,
    float*       __restrict__ out)
{
    constexpr int W = 128, H = 128, C = 12;
    constexpr int PLANE  = H * W;        // 16384 floats
    constexpr int SAMPLE = C * PLANE;    // 196608 floats = 49152 float4

    const int n  = blockIdx.y;           // sample index (uniform)
    const int ws = w_starts[n] - PAD;    // [-4, 4], scalar
    const int hs = h_starts[n] - PAD;

    const float* __restrict__ xs = x   + (size_t)n * SAMPLE;
    float*       __restrict__ os = out + (size_t)n * SAMPLE;

    const int t       = threadIdx.x;
    const int base_f4 = blockIdx.x << 10;   // 1024 float4 per block

    #pragma unroll
    for (int k = 0; k < 4; ++k) {
        int f4idx = base_f4 + (k << 8) + t;     // [0, 49152)
        int elem  = f4idx << 2;
        int j0    = elem & (W - 1);             // output column (mult of 4)
        int i     = (elem >> 7) & (H - 1);      // output row
        int poff  = elem & ~(PLANE - 1);        // c * PLANE

        int si = i + hs;
        si = si < 0 ? 0 : (si > H - 1 ? H - 1 : si);

        const float* __restrict__ src_row = xs + poff + si * W;

        vf4 v;
        int sj = j0 + ws;                       // [-4, 128]

        if (sj >= 0 && sj <= W - 4) {
            const vf4* __restrict__ src4 = reinterpret_cast<const vf4*>(src_row);
            int q = sj >> 2;                    // [0, 31]
            int s = sj & 3;                     // wave-uniform
            vf4 A = src4[q];
            if (s == 0) {
                v = A;
            } else {
                vf4 B = src4[q + 1];            // q <= 30 when s >= 1
                if (s == 1)      v = (vf4){A.y, A.z, A.w, B.x};
                else if (s == 2) v = (vf4){A.z, A.w, B.x, B.y};
                else             v = (vf4){A.w, B.x, B.y, B.z};
            }
        } else {
            int j;
            j = sj + 0; j = j < 0 ? 0 : (j > W - 1 ? W - 1 : j); v.x = src_row[j];
            j = sj + 1; j = j < 0 ? 0 : (j > W - 1 ? W - 1 : j); v.y = src_row[j];
            j = sj + 2; j = j < 0 ? 0 : (j > W - 1 ? W - 1 : j); v.z = src_row[j];
            j = sj + 3; j = j < 0 ? 0 : (j > W - 1 ? W - 1 : j); v.w = src_row[j];
        }

        __builtin_nontemporal_store(v, reinterpret_cast<vf4*>(os + elem));
    }
}

extern "C" void kernel_launch(void* const* d_in, const int* in_sizes, int n_in,
                              void* d_out, int out_size, void* d_ws, size_t ws_size,
                              hipStream_t stream) {
    const float* x        = (const float*)d_in[0];
    const int*   h_starts = (const int*)d_in[1];
    const int*   w_starts = (const int*)d_in[2];
    float*       out      = (float*)d_out;

    // 49152 float4 per sample / (256 threads * 4 f4) = 48 blocks per sample
    dim3 grid(48, 256);
    dim3 block(256);

    random_shift_kernel<<<grid, block, 0, stream>>>(x, h_starts, w_starts, out);
}